// Round 10
// baseline (61.821 us; speedup 1.0000x reference)
//
#include <hip/hip_runtime.h>
#include <math.h>

namespace {
constexpr int B = 4;
constexpr int S = 4096;
constexpr int H = 2048;
constexpr int DR = 3;          // depth
constexpr int KSEL = 1365;     // int(4096/3)
constexpr int NBLK1 = 2048;    // score blocks: 4 waves x 2 tokens
constexpr unsigned FONE = 0x3F800000u;    // bits of 1.0f
}

// ---------------------------------------------------------------------------
// K1: raw[d][t] = dot(hidden[t,:], w[d,:]); sc = sigmoid(raw) (exp-form f32,
//     matches XLA). LDS-staged weights, 2 tokens/wave interleaved. Fills
//     masks[0] (all-ones). Loss partials plane-major per block.
//     NOTE: this round launches K1 TWICE (idempotent) as instrumentation —
//     delta vs single-launch baseline measures K1's true duration, and the
//     second pass measures the L3-resident speed of the same loop.
// ---------------------------------------------------------------------------
__global__ __launch_bounds__(256) void ecr_scores(const float* __restrict__ hid,
                                                  const float* __restrict__ w,
                                                  unsigned* __restrict__ keys,
                                                  float* __restrict__ partials,
                                                  float* __restrict__ out) {
    __shared__ float wl[DR * H];        // 24 KB staged weights
    __shared__ float s2l[4][DR];
    const float4* wg4 = reinterpret_cast<const float4*>(w);
    float4* wl4 = reinterpret_cast<float4*>(wl);
    for (int i = threadIdx.x; i < DR * H / 4; i += 256) wl4[i] = wg4[i];
    __syncthreads();

    const int wave = threadIdx.x >> 6;
    const int lane = threadIdx.x & 63;
    const int gw = blockIdx.x * 4 + wave;             // 0..8191
    const int t0 = gw * 2;                            // flat token = b*S+s
    const float4* wl4_0 = reinterpret_cast<const float4*>(wl);
    const float4* wl4_1 = wl4_0 + (H / 4);
    const float4* wl4_2 = wl4_0 + 2 * (H / 4);
    const float4* h40 = reinterpret_cast<const float4*>(hid) + (size_t)t0 * (H / 4);
    const float4* h41 = h40 + (H / 4);

    float a00 = 0.f, a01 = 0.f, a02 = 0.f;            // token 0, depths 0..2
    float a10 = 0.f, a11 = 0.f, a12 = 0.f;            // token 1
#pragma unroll
    for (int j = 0; j < 8; ++j) {                     // 2x float4 per lane/iter
        const int idx = j * 64 + lane;
        const float4 hv0 = h40[idx];
        const float4 hv1 = h41[idx];
        const float4 w0 = wl4_0[idx];
        const float4 w1 = wl4_1[idx];
        const float4 w2 = wl4_2[idx];
        a00 = fmaf(hv0.x, w0.x, a00); a10 = fmaf(hv1.x, w0.x, a10);
        a00 = fmaf(hv0.y, w0.y, a00); a10 = fmaf(hv1.y, w0.y, a10);
        a00 = fmaf(hv0.z, w0.z, a00); a10 = fmaf(hv1.z, w0.z, a10);
        a00 = fmaf(hv0.w, w0.w, a00); a10 = fmaf(hv1.w, w0.w, a10);
        a01 = fmaf(hv0.x, w1.x, a01); a11 = fmaf(hv1.x, w1.x, a11);
        a01 = fmaf(hv0.y, w1.y, a01); a11 = fmaf(hv1.y, w1.y, a11);
        a01 = fmaf(hv0.z, w1.z, a01); a11 = fmaf(hv1.z, w1.z, a11);
        a01 = fmaf(hv0.w, w1.w, a01); a11 = fmaf(hv1.w, w1.w, a11);
        a02 = fmaf(hv0.x, w2.x, a02); a12 = fmaf(hv1.x, w2.x, a12);
        a02 = fmaf(hv0.y, w2.y, a02); a12 = fmaf(hv1.y, w2.y, a12);
        a02 = fmaf(hv0.z, w2.z, a02); a12 = fmaf(hv1.z, w2.z, a12);
        a02 = fmaf(hv0.w, w2.w, a02); a12 = fmaf(hv1.w, w2.w, a12);
    }
#pragma unroll
    for (int off = 32; off >= 1; off >>= 1) {         // 64-lane butterfly x6
        a00 += __shfl_xor(a00, off); a01 += __shfl_xor(a01, off);
        a02 += __shfl_xor(a02, off); a10 += __shfl_xor(a10, off);
        a11 += __shfl_xor(a11, off); a12 += __shfl_xor(a12, off);
    }
    if (lane == 0) {
        const float s00 = 1.0f / (1.0f + expf(-a00));
        const float s01 = 1.0f / (1.0f + expf(-a01));
        const float s02 = 1.0f / (1.0f + expf(-a02));
        const float s10 = 1.0f / (1.0f + expf(-a10));
        const float s11 = 1.0f / (1.0f + expf(-a11));
        const float s12 = 1.0f / (1.0f + expf(-a12));
        uint2 kk;
        kk.x = __float_as_uint(s00);
        kk.y = __float_as_uint(s10);
        *reinterpret_cast<uint2*>(keys + t0) = kk;    // t0 even -> 8B aligned
        s2l[wave][0] = 1.0f / (1.0f + expf(-s00)) + 1.0f / (1.0f + expf(-s10));
        s2l[wave][1] = 1.0f / (1.0f + expf(-s01)) + 1.0f / (1.0f + expf(-s11));
        s2l[wave][2] = 1.0f / (1.0f + expf(-s02)) + 1.0f / (1.0f + expf(-s12));
    }
    __syncthreads();
    if (threadIdx.x == 0) {
        float p0 = 0.f, p1 = 0.f, p2 = 0.f;
#pragma unroll
        for (int v = 0; v < 4; ++v) { p0 += s2l[v][0]; p1 += s2l[v][1]; p2 += s2l[v][2]; }
        partials[0 * NBLK1 + blockIdx.x] = p0;        // plane-major per block
        partials[1 * NBLK1 + blockIdx.x] = p1;
        partials[2 * NBLK1 + blockIdx.x] = p2;
    }
    // masks[0] plane (all ones): 8 consecutive floats per block, coalesced.
    if (threadIdx.x < 8)
        out[B * S + 1 + blockIdx.x * 8 + threadIdx.x] = 1.0f;
}

// ---------------------------------------------------------------------------
// K2: per-batch exact top-KSEL (value desc, index asc), strided ownership
//     (all accesses lane-consecutive). Fast path when count(key==1.0f) >=
//     KSEL. Stable tie rank via 8 per-level block prefix scans. Block 0
//     fuses the balancing-loss reduction.
// ---------------------------------------------------------------------------
__global__ __launch_bounds__(512) void ecr_select(const unsigned* __restrict__ keys,
                                                  const float* __restrict__ partials,
                                                  float* __restrict__ out) {
    const int b = blockIdx.x;
    const int t = threadIdx.x;
    const int wave = t >> 6;
    const int lane = t & 63;

    __shared__ int wsum[2][8];
    __shared__ int wscan[8];

    // 8 strided keys per thread: global index of kr[i] is i*512 + t
    unsigned kr[8];
#pragma unroll
    for (int i = 0; i < 8; ++i) kr[i] = keys[b * S + i * 512 + t];

    // ---- fast path probe: count keys == 1.0f ----
    int c = 0;
#pragma unroll
    for (int i = 0; i < 8; ++i) c += (kr[i] == FONE);
#pragma unroll
    for (int off = 32; off >= 1; off >>= 1) c += __shfl_xor(c, off);
    if (lane == 0) wsum[0][wave] = c;
    __syncthreads();
    int tot1 = 0;
#pragma unroll
    for (int w2 = 0; w2 < 8; ++w2) tot1 += wsum[0][w2];

    unsigned vstar;
    int m;                                            // ties accepted (lowest index)
    if (tot1 >= KSEL) {                               // block-uniform decision
        vstar = FONE;                                 // nothing can exceed 1.0f
        m = KSEL;
    } else {
        // ---- general bitwise binary search, 1 barrier per iteration ----
        unsigned v = 0;
        int pb = 1;
        for (int bit = 29; bit >= 0; --bit) {
            const unsigned cand = v | (1u << bit);
            int cc = 0;
#pragma unroll
            for (int i = 0; i < 8; ++i) cc += (kr[i] >= cand);
#pragma unroll
            for (int off = 32; off >= 1; off >>= 1) cc += __shfl_xor(cc, off);
            if (lane == 0) wsum[pb][wave] = cc;
            __syncthreads();
            int tot = 0;
#pragma unroll
            for (int w2 = 0; w2 < 8; ++w2) tot += wsum[pb][w2];
            if (tot >= KSEL) v = cand;
            pb ^= 1;
        }
        vstar = v;
        int cg = 0;
#pragma unroll
        for (int i = 0; i < 8; ++i) cg += (kr[i] > vstar);
#pragma unroll
        for (int off = 32; off >= 1; off >>= 1) cg += __shfl_xor(cg, off);
        if (lane == 0) wsum[pb][wave] = cg;
        __syncthreads();
        int g = 0;
#pragma unroll
        for (int w2 = 0; w2 < 8; ++w2) g += wsum[pb][w2];
        m = KSEL - g;
    }
    __syncthreads();

    // ---- stable tie ranks, level by level (global index = i*512 + t) ----
    int rank[8];
    int cum = 0;                                      // ties in levels < i
    for (int i = 0; i < 8; ++i) {
        const int tci = (kr[i] == vstar) ? 1 : 0;
        int sc = tci;                                 // inclusive wave scan
#pragma unroll
        for (int off = 1; off <= 32; off <<= 1) {
            const int o = __shfl_up(sc, off);
            if (lane >= off) sc += o;
        }
        if (lane == 63) wscan[wave] = sc;
        __syncthreads();
        int base = 0, tot = 0;
#pragma unroll
        for (int w2 = 0; w2 < 8; ++w2) {
            if (w2 < wave) base += wscan[w2];
            tot += wscan[w2];
        }
        rank[i] = cum + base + (sc - tci);            // ties with smaller index
        cum += tot;
        __syncthreads();                              // before wscan reuse
    }

    // ---- emit depth + masks[1,2], all lane-consecutive (coalesced) ----
    float* depth  = out;                              // [B*S]
    float* masks1 = out + B * S + 1 + 1 * B * S;      // [B*S]
    float* masks2 = out + B * S + 1 + 2 * B * S;      // [B*S]
    const int s0 = b * S + t;
#pragma unroll
    for (int i = 0; i < 8; ++i) {
        int sel;
        if (kr[i] > vstar) sel = 1;
        else if (kr[i] == vstar) sel = (rank[i] < m) ? 1 : 0;
        else sel = 0;
        const float fsel = sel ? 1.0f : 0.0f;
        depth[s0 + i * 512]  = sel ? 3.0f : 1.0f;
        masks1[s0 + i * 512] = fsel;
        masks2[s0 + i * 512] = fsel;
    }

    // ---- block 0: fused balancing-loss reduction (plane-major partials) ----
    if (b == 0) {
        __shared__ double red[3][8];
        const float4* p4 = reinterpret_cast<const float4*>(partials);
        // 2048 floats per plane = 512 float4 -> exactly one per thread
        const float4 v0 = p4[t];
        const float4 v1 = p4[NBLK1 / 4 + t];
        const float4 v2 = p4[NBLK1 / 2 + t];
        double a0 = (double)v0.x + (double)v0.y + (double)v0.z + (double)v0.w;
        double a1 = (double)v1.x + (double)v1.y + (double)v1.z + (double)v1.w;
        double a2 = (double)v2.x + (double)v2.y + (double)v2.z + (double)v2.w;
#pragma unroll
        for (int off = 32; off >= 1; off >>= 1) {
            a0 += __shfl_xor(a0, off);
            a1 += __shfl_xor(a1, off);
            a2 += __shfl_xor(a2, off);
        }
        if (lane == 0) { red[0][wave] = a0; red[1][wave] = a1; red[2][wave] = a2; }
        __syncthreads();
        if (t == 0) {
            double s0d = 0.0, s1d = 0.0, s2d = 0.0;
#pragma unroll
            for (int w2 = 0; w2 < 8; ++w2) { s0d += red[0][w2]; s1d += red[1][w2]; s2d += red[2][w2]; }
            const double n = (double)(B * S);
            const double lt = log(1.0 / 3.0);
            double l = (lt - log(s0d / n)) + (lt - log(s1d / n)) + (lt - log(s2d / n));
            out[B * S] = (float)(l * (1.0 / 3.0) / 3.0);
        }
    }
}

extern "C" void kernel_launch(void* const* d_in, const int* in_sizes, int n_in,
                              void* d_out, int out_size, void* d_ws, size_t ws_size,
                              hipStream_t stream) {
    const float* hid = (const float*)d_in[0];     // [B,S,H] f32
    const float* w   = (const float*)d_in[1];     // [DR,H] f32
    float* out = (float*)d_out;                   // depth[B*S] | loss | masks[DR*B*S]

    unsigned* keys  = (unsigned*)d_ws;                                   // B*S uints (64 KiB)
    float* partials = (float*)((char*)d_ws + (size_t)B * S * sizeof(unsigned)); // 3*NBLK1 f32 (24 KiB)

    // INSTRUMENTATION: scores launched twice (idempotent). total - 37.0us
    // from round 9 == duration of one scores pass (second pass L3-warm).
    ecr_scores<<<NBLK1, 256, 0, stream>>>(hid, w, keys, partials, out);
    ecr_scores<<<NBLK1, 256, 0, stream>>>(hid, w, keys, partials, out);
    ecr_select<<<B, 512, 0, stream>>>(keys, partials, out);
}

// Round 11
// 34.814 us; speedup vs baseline: 1.7758x; 1.7758x over previous
//
#include <hip/hip_runtime.h>
#include <math.h>

namespace {
constexpr int B = 4;
constexpr int S = 4096;
constexpr int H = 2048;
constexpr int DR = 3;          // depth
constexpr int KSEL = 1365;     // int(4096/3)
constexpr int NBLK1 = 2048;    // score blocks: 4 waves x 2 tokens
constexpr unsigned FONE = 0x3F800000u;    // bits of 1.0f
}

// ---------------------------------------------------------------------------
// K1: raw[d][t] = dot(hidden[t,:], w[d,:]); sc = sigmoid(raw) (exp-form f32,
//     matches XLA). LDS-staged weights, 2 tokens/wave interleaved (best
//     measured). Fills masks[0] (all-ones). Partials plane-major per block.
//     Measured: ~25 us (~86% of 6.3 TB/s ceiling) -> near memory roofline.
// ---------------------------------------------------------------------------
__global__ __launch_bounds__(256) void ecr_scores(const float* __restrict__ hid,
                                                  const float* __restrict__ w,
                                                  unsigned* __restrict__ keys,
                                                  float* __restrict__ partials,
                                                  float* __restrict__ out) {
    __shared__ float wl[DR * H];        // 24 KB staged weights
    __shared__ float s2l[4][DR];
    const float4* wg4 = reinterpret_cast<const float4*>(w);
    float4* wl4 = reinterpret_cast<float4*>(wl);
    for (int i = threadIdx.x; i < DR * H / 4; i += 256) wl4[i] = wg4[i];
    __syncthreads();

    const int wave = threadIdx.x >> 6;
    const int lane = threadIdx.x & 63;
    const int gw = blockIdx.x * 4 + wave;             // 0..8191
    const int t0 = gw * 2;                            // flat token = b*S+s
    const float4* wl4_0 = reinterpret_cast<const float4*>(wl);
    const float4* wl4_1 = wl4_0 + (H / 4);
    const float4* wl4_2 = wl4_0 + 2 * (H / 4);
    const float4* h40 = reinterpret_cast<const float4*>(hid) + (size_t)t0 * (H / 4);
    const float4* h41 = h40 + (H / 4);

    float a00 = 0.f, a01 = 0.f, a02 = 0.f;            // token 0, depths 0..2
    float a10 = 0.f, a11 = 0.f, a12 = 0.f;            // token 1
#pragma unroll
    for (int j = 0; j < 8; ++j) {                     // 2x float4 per lane/iter
        const int idx = j * 64 + lane;
        const float4 hv0 = h40[idx];
        const float4 hv1 = h41[idx];
        const float4 w0 = wl4_0[idx];
        const float4 w1 = wl4_1[idx];
        const float4 w2 = wl4_2[idx];
        a00 = fmaf(hv0.x, w0.x, a00); a10 = fmaf(hv1.x, w0.x, a10);
        a00 = fmaf(hv0.y, w0.y, a00); a10 = fmaf(hv1.y, w0.y, a10);
        a00 = fmaf(hv0.z, w0.z, a00); a10 = fmaf(hv1.z, w0.z, a10);
        a00 = fmaf(hv0.w, w0.w, a00); a10 = fmaf(hv1.w, w0.w, a10);
        a01 = fmaf(hv0.x, w1.x, a01); a11 = fmaf(hv1.x, w1.x, a11);
        a01 = fmaf(hv0.y, w1.y, a01); a11 = fmaf(hv1.y, w1.y, a11);
        a01 = fmaf(hv0.z, w1.z, a01); a11 = fmaf(hv1.z, w1.z, a11);
        a01 = fmaf(hv0.w, w1.w, a01); a11 = fmaf(hv1.w, w1.w, a11);
        a02 = fmaf(hv0.x, w2.x, a02); a12 = fmaf(hv1.x, w2.x, a12);
        a02 = fmaf(hv0.y, w2.y, a02); a12 = fmaf(hv1.y, w2.y, a12);
        a02 = fmaf(hv0.z, w2.z, a02); a12 = fmaf(hv1.z, w2.z, a12);
        a02 = fmaf(hv0.w, w2.w, a02); a12 = fmaf(hv1.w, w2.w, a12);
    }
#pragma unroll
    for (int off = 32; off >= 1; off >>= 1) {         // 64-lane butterfly x6
        a00 += __shfl_xor(a00, off); a01 += __shfl_xor(a01, off);
        a02 += __shfl_xor(a02, off); a10 += __shfl_xor(a10, off);
        a11 += __shfl_xor(a11, off); a12 += __shfl_xor(a12, off);
    }
    if (lane == 0) {
        const float s00 = 1.0f / (1.0f + expf(-a00));
        const float s01 = 1.0f / (1.0f + expf(-a01));
        const float s02 = 1.0f / (1.0f + expf(-a02));
        const float s10 = 1.0f / (1.0f + expf(-a10));
        const float s11 = 1.0f / (1.0f + expf(-a11));
        const float s12 = 1.0f / (1.0f + expf(-a12));
        uint2 kk;
        kk.x = __float_as_uint(s00);
        kk.y = __float_as_uint(s10);
        *reinterpret_cast<uint2*>(keys + t0) = kk;    // t0 even -> 8B aligned
        s2l[wave][0] = 1.0f / (1.0f + expf(-s00)) + 1.0f / (1.0f + expf(-s10));
        s2l[wave][1] = 1.0f / (1.0f + expf(-s01)) + 1.0f / (1.0f + expf(-s11));
        s2l[wave][2] = 1.0f / (1.0f + expf(-s02)) + 1.0f / (1.0f + expf(-s12));
    }
    __syncthreads();
    if (threadIdx.x == 0) {
        float p0 = 0.f, p1 = 0.f, p2 = 0.f;
#pragma unroll
        for (int v = 0; v < 4; ++v) { p0 += s2l[v][0]; p1 += s2l[v][1]; p2 += s2l[v][2]; }
        partials[0 * NBLK1 + blockIdx.x] = p0;        // plane-major per block
        partials[1 * NBLK1 + blockIdx.x] = p1;
        partials[2 * NBLK1 + blockIdx.x] = p2;
    }
    // masks[0] plane (all ones): 8 consecutive floats per block, coalesced.
    if (threadIdx.x < 8)
        out[B * S + 1 + blockIdx.x * 8 + threadIdx.x] = 1.0f;
}

// ---------------------------------------------------------------------------
// K2: 32 blocks = 4 batches x 8 slices of 512 tokens. Each block redundantly
//     loads its batch's full 4096 keys (16 KB, LLC-hot), computes vstar/m
//     independently (fast path: one count; else bitwise binary search),
//     counts ties BEFORE its slice from the in-register copy, then ranks and
//     writes only its 512-token slice (fully coalesced, ~4 barriers total).
//     Tie order = global index asc (value desc, index asc, stable).
//     Block 0 additionally reduces the balancing loss.
// ---------------------------------------------------------------------------
__global__ __launch_bounds__(256) void ecr_select(const unsigned* __restrict__ keys,
                                                  const float* __restrict__ partials,
                                                  float* __restrict__ out) {
    const int g = blockIdx.x;                         // 0..31
    const int b = g >> 3;                             // batch
    const int j = g & 7;                              // slice
    const int t = threadIdx.x;                        // 0..255
    const int wave = t >> 6;
    const int lane = t & 63;

    __shared__ int wsum[2][4];
    __shared__ int cred[4];
    __shared__ int sA[4], sB[4];

    // ---- load the batch's full key set: thread t -> uint4s {t,t+256,t+512,t+768}
    const uint4* kp = reinterpret_cast<const uint4*>(keys + b * S);
    unsigned kr[16];
    int u4idx[4];
#pragma unroll
    for (int q = 0; q < 4; ++q) {
        const int ui = t + 256 * q;                   // uint4 index, 0..1023
        u4idx[q] = ui;
        const uint4 v = kp[ui];
        kr[4 * q + 0] = v.x; kr[4 * q + 1] = v.y;
        kr[4 * q + 2] = v.z; kr[4 * q + 3] = v.w;
    }

    // ---- fast-path probe: count keys == 1.0f over the whole batch ----
    int c = 0;
#pragma unroll
    for (int i = 0; i < 16; ++i) c += (kr[i] == FONE);
#pragma unroll
    for (int off = 32; off >= 1; off >>= 1) c += __shfl_xor(c, off);
    if (lane == 0) wsum[0][wave] = c;
    __syncthreads();
    int tot1 = 0;
#pragma unroll
    for (int w2 = 0; w2 < 4; ++w2) tot1 += wsum[0][w2];

    unsigned vstar;
    int m;                                            // ties accepted (lowest index)
    if (tot1 >= KSEL) {                               // block-uniform decision
        vstar = FONE;
        m = KSEL;
    } else {
        unsigned v = 0;
        int pb = 1;
        for (int bit = 29; bit >= 0; --bit) {
            const unsigned cand = v | (1u << bit);
            int cc = 0;
#pragma unroll
            for (int i = 0; i < 16; ++i) cc += (kr[i] >= cand);
#pragma unroll
            for (int off = 32; off >= 1; off >>= 1) cc += __shfl_xor(cc, off);
            if (lane == 0) wsum[pb][wave] = cc;
            __syncthreads();
            int tot = 0;
#pragma unroll
            for (int w2 = 0; w2 < 4; ++w2) tot += wsum[pb][w2];
            if (tot >= KSEL) v = cand;
            pb ^= 1;
        }
        vstar = v;
        int cg = 0;
#pragma unroll
        for (int i = 0; i < 16; ++i) cg += (kr[i] > vstar);
#pragma unroll
        for (int off = 32; off >= 1; off >>= 1) cg += __shfl_xor(cg, off);
        if (lane == 0) wsum[pb][wave] = cg;
        __syncthreads();
        int g2 = 0;
#pragma unroll
        for (int w2 = 0; w2 < 4; ++w2) g2 += wsum[pb][w2];
        m = KSEL - g2;
    }
    __syncthreads();

    // ---- ties with global index < slice start (j*512 <=> uint4 < j*128) ----
    int pc = 0;
#pragma unroll
    for (int q = 0; q < 4; ++q) {
        if (u4idx[q] < j * 128) {
#pragma unroll
            for (int cidx = 0; cidx < 4; ++cidx) pc += (kr[4 * q + cidx] == vstar);
        }
    }
#pragma unroll
    for (int off = 32; off >= 1; off >>= 1) pc += __shfl_xor(pc, off);
    if (lane == 0) cred[wave] = pc;
    __syncthreads();
    int cum = 0;
#pragma unroll
    for (int w2 = 0; w2 < 4; ++w2) cum += cred[w2];

    // ---- slice keys: token a = j*512 + t, token b = a + 256 (L1/L2-hot) ----
    const int ia = b * S + j * 512 + t;
    const unsigned ka = keys[ia];
    const unsigned kb = keys[ia + 256];
    const int fa = (ka == vstar) ? 1 : 0;
    const int fb = (kb == vstar) ? 1 : 0;

    int sa = fa, sb = fb;                             // inclusive wave scans
#pragma unroll
    for (int off = 1; off <= 32; off <<= 1) {
        const int oa = __shfl_up(sa, off);
        const int ob = __shfl_up(sb, off);
        if (lane >= off) { sa += oa; sb += ob; }
    }
    if (lane == 63) { sA[wave] = sa; sB[wave] = sb; }
    __syncthreads();
    int baseA = 0, totA = 0, baseB = 0;
#pragma unroll
    for (int w2 = 0; w2 < 4; ++w2) {
        if (w2 < wave) { baseA += sA[w2]; baseB += sB[w2]; }
        totA += sA[w2];
    }
    const int rank_a = cum + baseA + (sa - fa);
    const int rank_b = cum + totA + baseB + (sb - fb);

    // ---- emit depth + masks[1,2] for the slice (coalesced) ----
    const int sel_a = (ka > vstar) ? 1 : ((ka == vstar) ? (rank_a < m ? 1 : 0) : 0);
    const int sel_b = (kb > vstar) ? 1 : ((kb == vstar) ? (rank_b < m ? 1 : 0) : 0);
    float* depth  = out;                              // [B*S]
    float* masks1 = out + B * S + 1 + 1 * B * S;
    float* masks2 = out + B * S + 1 + 2 * B * S;
    depth[ia]        = sel_a ? 3.0f : 1.0f;
    depth[ia + 256]  = sel_b ? 3.0f : 1.0f;
    const float fsa = sel_a ? 1.0f : 0.0f;
    const float fsb = sel_b ? 1.0f : 0.0f;
    masks1[ia]       = fsa;
    masks1[ia + 256] = fsb;
    masks2[ia]       = fsa;
    masks2[ia + 256] = fsb;

    // ---- block 0: fused balancing-loss reduction (plane-major partials) ----
    if (g == 0) {
        __shared__ double red[3][4];
        const float4* p4 = reinterpret_cast<const float4*>(partials);
        double a0 = 0.0, a1 = 0.0, a2 = 0.0;
        for (int i = t; i < NBLK1 / 4; i += 256) {    // 512 float4 per plane
            const float4 v0 = p4[i];
            const float4 v1 = p4[NBLK1 / 4 + i];
            const float4 v2 = p4[NBLK1 / 2 + i];
            a0 += (double)v0.x + (double)v0.y + (double)v0.z + (double)v0.w;
            a1 += (double)v1.x + (double)v1.y + (double)v1.z + (double)v1.w;
            a2 += (double)v2.x + (double)v2.y + (double)v2.z + (double)v2.w;
        }
#pragma unroll
        for (int off = 32; off >= 1; off >>= 1) {
            a0 += __shfl_xor(a0, off);
            a1 += __shfl_xor(a1, off);
            a2 += __shfl_xor(a2, off);
        }
        if (lane == 0) { red[0][wave] = a0; red[1][wave] = a1; red[2][wave] = a2; }
        __syncthreads();
        if (t == 0) {
            double s0d = 0.0, s1d = 0.0, s2d = 0.0;
#pragma unroll
            for (int w2 = 0; w2 < 4; ++w2) { s0d += red[0][w2]; s1d += red[1][w2]; s2d += red[2][w2]; }
            const double n = (double)(B * S);
            const double lt = log(1.0 / 3.0);
            double l = (lt - log(s0d / n)) + (lt - log(s1d / n)) + (lt - log(s2d / n));
            out[B * S] = (float)(l * (1.0 / 3.0) / 3.0);
        }
    }
}

extern "C" void kernel_launch(void* const* d_in, const int* in_sizes, int n_in,
                              void* d_out, int out_size, void* d_ws, size_t ws_size,
                              hipStream_t stream) {
    const float* hid = (const float*)d_in[0];     // [B,S,H] f32
    const float* w   = (const float*)d_in[1];     // [DR,H] f32
    float* out = (float*)d_out;                   // depth[B*S] | loss | masks[DR*B*S]

    unsigned* keys  = (unsigned*)d_ws;                                   // B*S uints (64 KiB)
    float* partials = (float*)((char*)d_ws + (size_t)B * S * sizeof(unsigned)); // 3*NBLK1 f32 (24 KiB)

    ecr_scores<<<NBLK1, 256, 0, stream>>>(hid, w, keys, partials, out);
    ecr_select<<<B * 8, 256, 0, stream>>>(keys, partials, out);
}